// Round 3
// baseline (229.195 us; speedup 1.0000x reference)
//
#include <hip/hip_runtime.h>
#include <hip/hip_bf16.h>
#include <math.h>

// Problem constants
#define BQ 128
#define PP 256
#define MQ 16
#define MP 32
#define DD 768
#define MROWS (BQ*MQ)   // 2048
#define NROWS (PP*MP)   // 8192

typedef __bf16 bf16x8 __attribute__((ext_vector_type(8)));
typedef float  f32x4  __attribute__((ext_vector_type(4)));

// ---------- fp32 -> bf16 RTNE ----------
__device__ inline ushort bf16r(float f) {
    unsigned u = __float_as_uint(f);
    return (ushort)((u + 0x7FFFu + ((u >> 16) & 1u)) >> 16);
}

__global__ void conv_bf16_v4(const float4* __restrict__ in, ushort4* __restrict__ out, int n4) {
    int idx = blockIdx.x * blockDim.x + threadIdx.x;
    if (idx < n4) {
        float4 x = in[idx];
        ushort4 o;
        o.x = bf16r(x.x); o.y = bf16r(x.y); o.z = bf16r(x.z); o.w = bf16r(x.w);
        out[idx] = o;
    }
}

// ---------- fused GEMM (128x128 bf16 MFMA tile) + dual top-k selection ----------
// Tile = 8 q-batches x 4 passages = 32 complete (b,p) 16x32 sim blocks.
// GEMM acc -> LDS tile (stride 132 floats: 4-row-apart stores are 2-way bank
// aliased = free, m136) -> in-kernel selection, 8 pairs per wave.
// Selection keys truncated to top 16 bits: error << absmax budget, halves the
// serial radix descent (16 iterations).
#define BM 128
#define BN 128
#define BK 32
#define LDSU 32    // ushorts per staging row (64 B, unpadded for global_load_lds)
#define TLS 132    // tile LDS stride in floats (16B-aligned rows, 2-way banks)

__device__ inline void load16_to_lds(const ushort* g, ushort* l) {
    __builtin_amdgcn_global_load_lds(
        (const __attribute__((address_space(1))) unsigned int*)(g),
        (__attribute__((address_space(3))) unsigned int*)(l),
        16, 0, 0);
}

__device__ inline float key_to_float(unsigned kk) {
    return (kk & 0x80000000u) ? __uint_as_float(kk & 0x7FFFFFFFu)
                              : __uint_as_float(~kk);
}

__device__ inline float softplus_f(float x) {
    return (x > 20.f) ? x : log1pf(expf(x));
}

__global__ __launch_bounds__(256) void gemm_select(const ushort* __restrict__ A,
                                                   const ushort* __restrict__ B,
                                                   const int* __restrict__ qm,
                                                   const int* __restrict__ pm,
                                                   const float* __restrict__ araw,
                                                   const float* __restrict__ braw,
                                                   float* __restrict__ logits) {
    __shared__ float smem[BM * TLS];          // 67584 B; staging aliases front
    ushort* sA = (ushort*)smem;               // 8 KB
    ushort* sB = (ushort*)smem + BM * LDSU;   // 8 KB

    const int tid  = threadIdx.x;
    const int lane = tid & 63;
    const int wid  = tid >> 6;        // 4 waves
    const int wr   = wid >> 1;
    const int wc   = wid & 1;
    const int tileM = blockIdx.y * BM;    // 8 q-batches: bBase = blockIdx.y*8
    const int tileN = blockIdx.x * BN;    // 4 passages:  pBase = blockIdx.x*4
    const int bBase = blockIdx.y * 8;
    const int pBase = blockIdx.x * 4;

    // ---- per-block mask words (wave-uniform, computed redundantly per wave)
    unsigned qw[8]; int nq[8];
    #pragma unroll
    for (int t = 0; t < 8; ++t) {
        bool v = (lane < MQ) && (qm[(bBase + t) * MQ + lane] != 0);
        unsigned long long bal = __ballot(v);
        qw[t] = (unsigned)bal;
        nq[t] = __popcll(bal);
    }
    unsigned pw[4]; int np_[4];
    #pragma unroll
    for (int t = 0; t < 4; ++t) {
        bool v = (lane < MP) && (pm[(pBase + t) * MP + lane] != 0);
        unsigned long long bal = __ballot(v);
        pw[t] = (unsigned)bal;
        np_[t] = __popcll(bal);
    }

    // ---- GEMM phase
    f32x4 acc[4][4];
    #pragma unroll
    for (int i = 0; i < 4; ++i)
        #pragma unroll
        for (int j = 0; j < 4; ++j) {
            f32x4 z = {0.f, 0.f, 0.f, 0.f};
            acc[i][j] = z;
        }

    const int lr  = lane >> 2;
    const int kcu = ((lane & 3) ^ ((lane >> 3) & 3)) << 3;  // swizzled k-offset
    const int r0    = lane & 15;
    const int q     = lane >> 4;
    const int physq = q ^ ((r0 >> 1) & 3);

    for (int k0 = 0; k0 < DD; k0 += BK) {
        #pragma unroll
        for (int c = 0; c < 2; ++c) {
            int chunk = wid + c * 4;
            int row   = chunk * 16 + lr;
            load16_to_lds(A + (size_t)(tileM + row) * DD + k0 + kcu, &sA[chunk * 16 * LDSU]);
            load16_to_lds(B + (size_t)(tileN + row) * DD + k0 + kcu, &sB[chunk * 16 * LDSU]);
        }
        __syncthreads();

        bf16x8 af[4], bfr[4];
        #pragma unroll
        for (int mi = 0; mi < 4; ++mi)
            af[mi] = *(const bf16x8*)(&sA[(wr * 64 + mi * 16 + r0) * LDSU + physq * 8]);
        #pragma unroll
        for (int ni = 0; ni < 4; ++ni)
            bfr[ni] = *(const bf16x8*)(&sB[(wc * 64 + ni * 16 + r0) * LDSU + physq * 8]);

        #pragma unroll
        for (int mi = 0; mi < 4; ++mi)
            #pragma unroll
            for (int ni = 0; ni < 4; ++ni)
                acc[mi][ni] = __builtin_amdgcn_mfma_f32_16x16x32_bf16(af[mi], bfr[ni], acc[mi][ni], 0, 0, 0);
        __syncthreads();
    }

    // ---- acc -> LDS tile (clobbers staging; all reads done per trailing sync)
    #pragma unroll
    for (int mi = 0; mi < 4; ++mi) {
        #pragma unroll
        for (int ni = 0; ni < 4; ++ni) {
            int col   = wc * 64 + ni * 16 + (lane & 15);
            int rbase = wr * 64 + mi * 16 + (lane >> 4) * 4;
            #pragma unroll
            for (int r = 0; r < 4; ++r)
                smem[(rbase + r) * TLS + col] = acc[mi][ni][r];
        }
    }
    __syncthreads();

    // ---- selection phase: 8 pairs per wave
    float aco = softplus_f(araw[0]);
    float bco = softplus_f(braw[0]);

    const int i  = lane >> 2;          // row within 16
    const int j0 = (lane & 3) << 3;    // col within 32

    #pragma unroll 1
    for (int u = 0; u < 8; ++u) {
        int pairIdx = wid * 8 + u;     // 0..31
        int bl = pairIdx >> 2;         // 0..7
        int pl = pairIdx & 3;          // 0..3

        int n = nq[bl] * np_[pl];      // >= 1
        int k = (4 * n) / 10; if (k < 1) k = 1;
        int l = (8 * n) / 10;

        const float* tp = &smem[(bl * 16 + i) * TLS + pl * 32 + j0];
        float4 va = *(const float4*)tp;
        float4 vb = *(const float4*)(tp + 4);
        float v[8] = {va.x, va.y, va.z, va.w, vb.x, vb.y, vb.z, vb.w};

        unsigned qv = (qw[bl] >> i) & 1u;
        unsigned pv = pw[pl] >> j0;

        unsigned key[8], key2[8];
        #pragma unroll
        for (int t = 0; t < 8; ++t) {
            unsigned uu = __float_as_uint(v[t]);
            unsigned kk = (uu & 0x80000000u) ? ~uu : (uu | 0x80000000u);
            bool val = (qv != 0u) && (((pv >> t) & 1u) != 0u);
            key[t]  = val ? (kk >> 16)    : 0u;
            key2[t] = val ? ((~kk) >> 16) : 0u;
        }

        unsigned T1 = 0u, T2 = 0u;
        for (int bit = 15; bit >= 0; --bit) {
            unsigned c1 = T1 | (1u << bit);
            unsigned c2 = T2 | (1u << bit);
            int cnt1 = 0, cnt2 = 0;
            #pragma unroll
            for (int t = 0; t < 8; ++t) {
                cnt1 += __popcll(__ballot(key[t]  >= c1));
                cnt2 += __popcll(__ballot(key2[t] >= c2));
            }
            if (cnt1 >= k) T1 = c1;
            if (cnt2 >= l) T2 = c2;
        }

        float S1 = 0.f, S2 = 0.f;
        int c1n = 0, c2n = 0;
        #pragma unroll
        for (int t = 0; t < 8; ++t) {
            if (key[t]  > T1) S1 += v[t];
            if (key2[t] > T2) S2 += v[t];
            c1n += __popcll(__ballot(key[t]  > T1));
            c2n += __popcll(__ballot(key2[t] > T2));
        }
        #pragma unroll
        for (int off = 32; off > 0; off >>= 1) {
            S1 += __shfl_xor(S1, off, 64);
            S2 += __shfl_xor(S2, off, 64);
        }

        float f1 = key_to_float(T1 << 16);
        float f2 = key_to_float(~(T2 << 16));
        float top = S1 + (float)(k - c1n) * f1;
        float bot = (l > 0) ? (S2 + (float)(l - c2n) * f2) : 0.f;

        if (lane == 0)
            logits[(bBase + bl) * PP + (pBase + pl)] = aco * top - bco * bot;
    }
}

// ---------- loss = mean_b (lse(logits[b,:]) - logits[b,b]) ----------
__global__ __launch_bounds__(256) void loss_kernel(const float* __restrict__ logits,
                                                   float* __restrict__ loss_out) {
    __shared__ float warr[4];
    const int lane = threadIdx.x & 63;
    const int wid  = threadIdx.x >> 6;
    float acc = 0.f;
    for (int r = wid; r < BQ; r += 4) {
        const float* row = logits + r * PP;
        float x0 = row[lane], x1 = row[lane + 64], x2 = row[lane + 128], x3 = row[lane + 192];
        float m = fmaxf(fmaxf(x0, x1), fmaxf(x2, x3));
        #pragma unroll
        for (int off = 32; off > 0; off >>= 1)
            m = fmaxf(m, __shfl_xor(m, off, 64));
        float s = expf(x0 - m) + expf(x1 - m) + expf(x2 - m) + expf(x3 - m);
        #pragma unroll
        for (int off = 32; off > 0; off >>= 1)
            s += __shfl_xor(s, off, 64);
        float lse = m + logf(s);
        float diag = row[r];
        acc += (lse - diag);
    }
    if (lane == 0) warr[wid] = acc;
    __syncthreads();
    if (threadIdx.x == 0)
        loss_out[0] = (warr[0] + warr[1] + warr[2] + warr[3]) / (float)BQ;
}

extern "C" void kernel_launch(void* const* d_in, const int* in_sizes, int n_in,
                              void* d_out, int out_size, void* d_ws, size_t ws_size,
                              hipStream_t stream) {
    const float* q  = (const float*)d_in[0];
    const float* pe = (const float*)d_in[1];
    const int*   qm = (const int*)d_in[2];
    const int*   pm = (const int*)d_in[3];
    const float* ar = (const float*)d_in[4];
    const float* br = (const float*)d_in[5];
    float* out = (float*)d_out;           // [0] = loss, [1..32768] = logits

    // workspace: qb | pb (bf16 copies)
    char* ws = (char*)d_ws;
    ushort* qb  = (ushort*)ws;
    ushort* pb  = (ushort*)(ws + (size_t)MROWS * DD * 2);

    // 1) convert fp32 -> bf16
    int nq4 = MROWS * DD / 4;
    int np4 = NROWS * DD / 4;
    conv_bf16_v4<<<(nq4 + 255) / 256, 256, 0, stream>>>((const float4*)q,  (ushort4*)qb, nq4);
    conv_bf16_v4<<<(np4 + 255) / 256, 256, 0, stream>>>((const float4*)pe, (ushort4*)pb, np4);

    // 2) fused sim-GEMM + dual top-k -> logits
    dim3 gg(NROWS / BN, MROWS / BM, 1);   // (64, 16)
    gemm_select<<<gg, 256, 0, stream>>>(qb, pb, qm, pm, ar, br, out + 1);

    // 3) loss
    loss_kernel<<<1, 256, 0, stream>>>(out + 1, out);
}

// Round 4
// 190.690 us; speedup vs baseline: 1.2019x; 1.2019x over previous
//
#include <hip/hip_runtime.h>
#include <hip/hip_bf16.h>
#include <math.h>

// Problem constants
#define BQ 128
#define PP 256
#define MQ 16
#define MP 32
#define DD 768
#define MROWS (BQ*MQ)   // 2048
#define NROWS (PP*MP)   // 8192

typedef __bf16 bf16x8 __attribute__((ext_vector_type(8)));
typedef float  f32x4  __attribute__((ext_vector_type(4)));

// ---------- fp32 -> bf16 RTNE ----------
__device__ inline ushort bf16r(float f) {
    unsigned u = __float_as_uint(f);
    return (ushort)((u + 0x7FFFu + ((u >> 16) & 1u)) >> 16);
}

__global__ void conv_bf16_v4(const float4* __restrict__ in, ushort4* __restrict__ out, int n4) {
    int idx = blockIdx.x * blockDim.x + threadIdx.x;
    if (idx < n4) {
        float4 x = in[idx];
        ushort4 o;
        o.x = bf16r(x.x); o.y = bf16r(x.y); o.z = bf16r(x.z); o.w = bf16r(x.w);
        out[idx] = o;
    }
}

// ---------- fused GEMM (128x128 bf16 MFMA tile) + register-resident selection ----
// Each wave's 4x4 acc quadrant (64x64) = 4 b-blocks x 2 p-blocks = 8 complete
// (b,p) 16x32 sim blocks. Selection runs straight from acc registers:
// lane holds 8 elems per block at row=(lane>>4)*4+(t&3), col=(t>>2)*16+(lane&15)
// (m89 C/D layout). No LDS score tile -> LDS = 16 KB staging only.
#define BM 128
#define BN 128
#define BK 32
#define LDSU 32    // ushorts per staging row (64 B, unpadded for global_load_lds)

__device__ inline void load16_to_lds(const ushort* g, ushort* l) {
    __builtin_amdgcn_global_load_lds(
        (const __attribute__((address_space(1))) unsigned int*)(g),
        (__attribute__((address_space(3))) unsigned int*)(l),
        16, 0, 0);
}

__device__ inline float key_to_float(unsigned kk) {
    return (kk & 0x80000000u) ? __uint_as_float(kk & 0x7FFFFFFFu)
                              : __uint_as_float(~kk);
}

__device__ inline float softplus_f(float x) {
    return (x > 20.f) ? x : log1pf(expf(x));
}

__global__ __launch_bounds__(256) void gemm_select(const ushort* __restrict__ A,
                                                   const ushort* __restrict__ B,
                                                   const int* __restrict__ qm,
                                                   const int* __restrict__ pm,
                                                   const float* __restrict__ araw,
                                                   const float* __restrict__ braw,
                                                   float* __restrict__ logits) {
    __shared__ ushort sA[BM * LDSU];   // 8 KB
    __shared__ ushort sB[BN * LDSU];   // 8 KB

    const int tid  = threadIdx.x;
    const int lane = tid & 63;
    const int wid  = tid >> 6;        // 4 waves
    const int wr   = wid >> 1;
    const int wc   = wid & 1;
    const int tileM = blockIdx.y * BM;
    const int tileN = blockIdx.x * BN;
    const int bBase = blockIdx.y * 8;
    const int pBase = blockIdx.x * 4;

    // ---- per-wave mask words: this wave's 4 q-blocks and 2 p-blocks
    unsigned qw[4]; int nq[4];
    #pragma unroll
    for (int t = 0; t < 4; ++t) {
        bool v = (lane < MQ) && (qm[(bBase + wr * 4 + t) * MQ + lane] != 0);
        unsigned long long bal = __ballot(v);
        qw[t] = (unsigned)bal;
        nq[t] = __popcll(bal);
    }
    unsigned pw[2]; int np_[2];
    #pragma unroll
    for (int t = 0; t < 2; ++t) {
        bool v = (lane < MP) && (pm[(pBase + wc * 2 + t) * MP + lane] != 0);
        unsigned long long bal = __ballot(v);
        pw[t] = (unsigned)bal;
        np_[t] = __popcll(bal);
    }

    // ---- GEMM phase
    f32x4 acc[4][4];
    #pragma unroll
    for (int i = 0; i < 4; ++i)
        #pragma unroll
        for (int j = 0; j < 4; ++j) {
            f32x4 z = {0.f, 0.f, 0.f, 0.f};
            acc[i][j] = z;
        }

    const int lr  = lane >> 2;
    const int kcu = ((lane & 3) ^ ((lane >> 3) & 3)) << 3;  // swizzled k-offset
    const int r0    = lane & 15;
    const int q     = lane >> 4;
    const int physq = q ^ ((r0 >> 1) & 3);

    for (int k0 = 0; k0 < DD; k0 += BK) {
        #pragma unroll
        for (int c = 0; c < 2; ++c) {
            int chunk = wid + c * 4;
            int row   = chunk * 16 + lr;
            load16_to_lds(A + (size_t)(tileM + row) * DD + k0 + kcu, &sA[chunk * 16 * LDSU]);
            load16_to_lds(B + (size_t)(tileN + row) * DD + k0 + kcu, &sB[chunk * 16 * LDSU]);
        }
        __syncthreads();

        bf16x8 af[4], bfr[4];
        #pragma unroll
        for (int mi = 0; mi < 4; ++mi)
            af[mi] = *(const bf16x8*)(&sA[(wr * 64 + mi * 16 + r0) * LDSU + physq * 8]);
        #pragma unroll
        for (int ni = 0; ni < 4; ++ni)
            bfr[ni] = *(const bf16x8*)(&sB[(wc * 64 + ni * 16 + r0) * LDSU + physq * 8]);

        #pragma unroll
        for (int mi = 0; mi < 4; ++mi)
            #pragma unroll
            for (int ni = 0; ni < 4; ++ni)
                acc[mi][ni] = __builtin_amdgcn_mfma_f32_16x16x32_bf16(af[mi], bfr[ni], acc[mi][ni], 0, 0, 0);
        __syncthreads();
    }

    // ---- selection phase: 8 pairs per wave, straight from acc registers
    float aco = softplus_f(araw[0]);
    float bco = softplus_f(braw[0]);
    const int rowb = (lane >> 4) * 4;   // C-layout row base for this lane
    const int colb = lane & 15;         // C-layout col within 16-fragment

    #pragma unroll 1
    for (int pair = 0; pair < 8; ++pair) {
        // wave-uniform switch keeps acc[]/SGPR-array indexing static
        f32x4 w0, w1; unsigned qwv, pwv; int nqv, npv;
        switch (pair) {
        case 0:  w0 = acc[0][0]; w1 = acc[0][1]; qwv = qw[0]; nqv = nq[0]; pwv = pw[0]; npv = np_[0]; break;
        case 1:  w0 = acc[0][2]; w1 = acc[0][3]; qwv = qw[0]; nqv = nq[0]; pwv = pw[1]; npv = np_[1]; break;
        case 2:  w0 = acc[1][0]; w1 = acc[1][1]; qwv = qw[1]; nqv = nq[1]; pwv = pw[0]; npv = np_[0]; break;
        case 3:  w0 = acc[1][2]; w1 = acc[1][3]; qwv = qw[1]; nqv = nq[1]; pwv = pw[1]; npv = np_[1]; break;
        case 4:  w0 = acc[2][0]; w1 = acc[2][1]; qwv = qw[2]; nqv = nq[2]; pwv = pw[0]; npv = np_[0]; break;
        case 5:  w0 = acc[2][2]; w1 = acc[2][3]; qwv = qw[2]; nqv = nq[2]; pwv = pw[1]; npv = np_[1]; break;
        case 6:  w0 = acc[3][0]; w1 = acc[3][1]; qwv = qw[3]; nqv = nq[3]; pwv = pw[0]; npv = np_[0]; break;
        default: w0 = acc[3][2]; w1 = acc[3][3]; qwv = qw[3]; nqv = nq[3]; pwv = pw[1]; npv = np_[1]; break;
        }

        int n = nqv * npv;            // >= 1
        int k = (4 * n) / 10; if (k < 1) k = 1;
        int l = (8 * n) / 10;

        float v[8] = {w0[0], w0[1], w0[2], w0[3], w1[0], w1[1], w1[2], w1[3]};
        unsigned key[8], key2[8];
        #pragma unroll
        for (int t = 0; t < 8; ++t) {
            int row = rowb + (t & 3);
            int col = (t >> 2) * 16 + colb;
            unsigned uu = __float_as_uint(v[t]);
            unsigned kk = (uu & 0x80000000u) ? ~uu : (uu | 0x80000000u);
            bool val = (((qwv >> row) & 1u) != 0u) && (((pwv >> col) & 1u) != 0u);
            key[t]  = val ? (kk >> 16)    : 0u;
            key2[t] = val ? ((~kk) >> 16) : 0u;
        }

        // MSB-first radix descent on 16-bit keys
        unsigned T1 = 0u, T2 = 0u;
        for (int bit = 15; bit >= 0; --bit) {
            unsigned c1 = T1 | (1u << bit);
            unsigned c2 = T2 | (1u << bit);
            int cnt1 = 0, cnt2 = 0;
            #pragma unroll
            for (int t = 0; t < 8; ++t) {
                cnt1 += __popcll(__ballot(key[t]  >= c1));
                cnt2 += __popcll(__ballot(key2[t] >= c2));
            }
            if (cnt1 >= k) T1 = c1;
            if (cnt2 >= l) T2 = c2;
        }

        // tie-corrected sums
        float S1 = 0.f, S2 = 0.f;
        int c1n = 0, c2n = 0;
        #pragma unroll
        for (int t = 0; t < 8; ++t) {
            if (key[t]  > T1) S1 += v[t];
            if (key2[t] > T2) S2 += v[t];
            c1n += __popcll(__ballot(key[t]  > T1));
            c2n += __popcll(__ballot(key2[t] > T2));
        }
        #pragma unroll
        for (int off = 32; off > 0; off >>= 1) {
            S1 += __shfl_xor(S1, off, 64);
            S2 += __shfl_xor(S2, off, 64);
        }

        float f1 = key_to_float(T1 << 16);
        float f2 = key_to_float(~(T2 << 16));
        float top = S1 + (float)(k - c1n) * f1;
        float bot = (l > 0) ? (S2 + (float)(l - c2n) * f2) : 0.f;

        if (lane == 0) {
            int mi = pair >> 1, nip = pair & 1;
            logits[(bBase + wr * 4 + mi) * PP + (pBase + wc * 2 + nip)] = aco * top - bco * bot;
        }
    }
}

// ---------- loss = mean_b (lse(logits[b,:]) - logits[b,b]) ----------
__global__ __launch_bounds__(256) void loss_kernel(const float* __restrict__ logits,
                                                   float* __restrict__ loss_out) {
    __shared__ float warr[4];
    const int lane = threadIdx.x & 63;
    const int wid  = threadIdx.x >> 6;
    float acc = 0.f;
    for (int r = wid; r < BQ; r += 4) {
        const float* row = logits + r * PP;
        float x0 = row[lane], x1 = row[lane + 64], x2 = row[lane + 128], x3 = row[lane + 192];
        float m = fmaxf(fmaxf(x0, x1), fmaxf(x2, x3));
        #pragma unroll
        for (int off = 32; off > 0; off >>= 1)
            m = fmaxf(m, __shfl_xor(m, off, 64));
        float s = expf(x0 - m) + expf(x1 - m) + expf(x2 - m) + expf(x3 - m);
        #pragma unroll
        for (int off = 32; off > 0; off >>= 1)
            s += __shfl_xor(s, off, 64);
        float lse = m + logf(s);
        float diag = row[r];
        acc += (lse - diag);
    }
    if (lane == 0) warr[wid] = acc;
    __syncthreads();
    if (threadIdx.x == 0)
        loss_out[0] = (warr[0] + warr[1] + warr[2] + warr[3]) / (float)BQ;
}

extern "C" void kernel_launch(void* const* d_in, const int* in_sizes, int n_in,
                              void* d_out, int out_size, void* d_ws, size_t ws_size,
                              hipStream_t stream) {
    const float* q  = (const float*)d_in[0];
    const float* pe = (const float*)d_in[1];
    const int*   qm = (const int*)d_in[2];
    const int*   pm = (const int*)d_in[3];
    const float* ar = (const float*)d_in[4];
    const float* br = (const float*)d_in[5];
    float* out = (float*)d_out;           // [0] = loss, [1..32768] = logits

    // workspace: qb | pb (bf16 copies)
    char* ws = (char*)d_ws;
    ushort* qb  = (ushort*)ws;
    ushort* pb  = (ushort*)(ws + (size_t)MROWS * DD * 2);

    // 1) convert fp32 -> bf16
    int nq4 = MROWS * DD / 4;
    int np4 = NROWS * DD / 4;
    conv_bf16_v4<<<(nq4 + 255) / 256, 256, 0, stream>>>((const float4*)q,  (ushort4*)qb, nq4);
    conv_bf16_v4<<<(np4 + 255) / 256, 256, 0, stream>>>((const float4*)pe, (ushort4*)pb, np4);

    // 2) fused sim-GEMM + dual top-k -> logits
    dim3 gg(NROWS / BN, MROWS / BM, 1);   // (64, 16)
    gemm_select<<<gg, 256, 0, stream>>>(qb, pb, qm, pm, ar, br, out + 1);

    // 3) loss
    loss_kernel<<<1, 256, 0, stream>>>(out + 1, out);
}

// Round 5
// 189.401 us; speedup vs baseline: 1.2101x; 1.0068x over previous
//
#include <hip/hip_runtime.h>
#include <hip/hip_bf16.h>
#include <math.h>

// Problem constants
#define BQ 128
#define PP 256
#define MQ 16
#define MP 32
#define DD 768
#define MROWS (BQ*MQ)   // 2048
#define NROWS (PP*MP)   // 8192

typedef __bf16 bf16x8 __attribute__((ext_vector_type(8)));
typedef float  f32x4  __attribute__((ext_vector_type(4)));

// ---------- fp32 -> bf16 RTNE ----------
__device__ inline ushort bf16r(float f) {
    unsigned u = __float_as_uint(f);
    return (ushort)((u + 0x7FFFu + ((u >> 16) & 1u)) >> 16);
}

__global__ void conv_bf16_v4(const float4* __restrict__ in, ushort4* __restrict__ out, int n4) {
    int idx = blockIdx.x * blockDim.x + threadIdx.x;
    if (idx < n4) {
        float4 x = in[idx];
        ushort4 o;
        o.x = bf16r(x.x); o.y = bf16r(x.y); o.z = bf16r(x.z); o.w = bf16r(x.w);
        out[idx] = o;
    }
}

// ---------- fused GEMM (64x128 bf16 MFMA tile) + register-resident selection ----
// 2048 blocks = 8 blocks/CU = 32 waves/CU (HW max) — R4 was grid-limited at 4.
// Wave quadrant 32x64 = acc[2][4] = 2 q-batches x 2 passages = 4 pairs/wave,
// selected straight from acc registers (m89 C/D layout:
// row=(lane>>4)*4+(t&3), col=(t>>2)*16+(lane&15)).
#define BM 64
#define BN 128
#define BK 32
#define LDSU 32    // ushorts per staging row (64 B, unpadded for global_load_lds)

__device__ inline void load16_to_lds(const ushort* g, ushort* l) {
    __builtin_amdgcn_global_load_lds(
        (const __attribute__((address_space(1))) unsigned int*)(g),
        (__attribute__((address_space(3))) unsigned int*)(l),
        16, 0, 0);
}

__device__ inline float key_to_float(unsigned kk) {
    return (kk & 0x80000000u) ? __uint_as_float(kk & 0x7FFFFFFFu)
                              : __uint_as_float(~kk);
}

__device__ inline float softplus_f(float x) {
    return (x > 20.f) ? x : log1pf(expf(x));
}

__global__ __launch_bounds__(256) void gemm_select(const ushort* __restrict__ A,
                                                   const ushort* __restrict__ B,
                                                   const int* __restrict__ qm,
                                                   const int* __restrict__ pm,
                                                   const float* __restrict__ araw,
                                                   const float* __restrict__ braw,
                                                   float* __restrict__ logits) {
    __shared__ ushort sA[BM * LDSU];   // 4 KB
    __shared__ ushort sB[BN * LDSU];   // 8 KB

    const int tid  = threadIdx.x;
    const int lane = tid & 63;
    const int wid  = tid >> 6;        // 4 waves, 2x2 grid over 64x128
    const int wr   = wid >> 1;        // 0..1 -> rows wr*32
    const int wc   = wid & 1;         // 0..1 -> cols wc*64
    const int tileM = blockIdx.y * BM;
    const int tileN = blockIdx.x * BN;
    const int bBase = blockIdx.y * 4;  // 4 q-batches per block
    const int pBase = blockIdx.x * 4;  // 4 passages per block

    // ---- per-wave mask words: this wave's 2 q-blocks and 2 p-blocks
    unsigned qw[2]; int nq[2];
    #pragma unroll
    for (int t = 0; t < 2; ++t) {
        bool v = (lane < MQ) && (qm[(bBase + wr * 2 + t) * MQ + lane] != 0);
        unsigned long long bal = __ballot(v);
        qw[t] = (unsigned)bal;
        nq[t] = __popcll(bal);
    }
    unsigned pw[2]; int np_[2];
    #pragma unroll
    for (int t = 0; t < 2; ++t) {
        bool v = (lane < MP) && (pm[(pBase + wc * 2 + t) * MP + lane] != 0);
        unsigned long long bal = __ballot(v);
        pw[t] = (unsigned)bal;
        np_[t] = __popcll(bal);
    }

    // ---- GEMM phase
    f32x4 acc[2][4];
    #pragma unroll
    for (int i = 0; i < 2; ++i)
        #pragma unroll
        for (int j = 0; j < 4; ++j) {
            f32x4 z = {0.f, 0.f, 0.f, 0.f};
            acc[i][j] = z;
        }

    const int lr  = lane >> 2;                               // row within 16-row chunk
    const int kcu = ((lane & 3) ^ ((lane >> 3) & 3)) << 3;   // swizzled logical k-offset
    const int r0    = lane & 15;
    const int q     = lane >> 4;
    const int physq = q ^ ((r0 >> 1) & 3);

    for (int k0 = 0; k0 < DD; k0 += BK) {
        // staging: A = 4 chunks of 16 rows, B = 8 chunks; wave w does
        // A-chunk w and B-chunks 2w, 2w+1 (3 loads/wave, lane-contiguous dest)
        {
            int rowA = wid * 16 + lr;
            load16_to_lds(A + (size_t)(tileM + rowA) * DD + k0 + kcu, &sA[wid * 16 * LDSU]);
            #pragma unroll
            for (int c = 0; c < 2; ++c) {
                int chunk = wid * 2 + c;
                int rowB  = chunk * 16 + lr;
                load16_to_lds(B + (size_t)(tileN + rowB) * DD + k0 + kcu, &sB[chunk * 16 * LDSU]);
            }
        }
        __syncthreads();

        bf16x8 af[2], bfr[4];
        #pragma unroll
        for (int mi = 0; mi < 2; ++mi)
            af[mi] = *(const bf16x8*)(&sA[(wr * 32 + mi * 16 + r0) * LDSU + physq * 8]);
        #pragma unroll
        for (int ni = 0; ni < 4; ++ni)
            bfr[ni] = *(const bf16x8*)(&sB[(wc * 64 + ni * 16 + r0) * LDSU + physq * 8]);

        #pragma unroll
        for (int mi = 0; mi < 2; ++mi)
            #pragma unroll
            for (int ni = 0; ni < 4; ++ni)
                acc[mi][ni] = __builtin_amdgcn_mfma_f32_16x16x32_bf16(af[mi], bfr[ni], acc[mi][ni], 0, 0, 0);
        __syncthreads();
    }

    // ---- selection phase: 4 pairs per wave, straight from acc registers
    float aco = softplus_f(araw[0]);
    float bco = softplus_f(braw[0]);
    const int rowb = (lane >> 4) * 4;   // C-layout row base for this lane
    const int colb = lane & 15;         // C-layout col within 16-fragment

    #pragma unroll 1
    for (int pair = 0; pair < 4; ++pair) {
        // wave-uniform switch keeps acc[]/SGPR indexing static
        f32x4 w0, w1; unsigned qwv, pwv; int nqv, npv;
        switch (pair) {
        case 0:  w0 = acc[0][0]; w1 = acc[0][1]; qwv = qw[0]; nqv = nq[0]; pwv = pw[0]; npv = np_[0]; break;
        case 1:  w0 = acc[0][2]; w1 = acc[0][3]; qwv = qw[0]; nqv = nq[0]; pwv = pw[1]; npv = np_[1]; break;
        case 2:  w0 = acc[1][0]; w1 = acc[1][1]; qwv = qw[1]; nqv = nq[1]; pwv = pw[0]; npv = np_[0]; break;
        default: w0 = acc[1][2]; w1 = acc[1][3]; qwv = qw[1]; nqv = nq[1]; pwv = pw[1]; npv = np_[1]; break;
        }

        int n = nqv * npv;            // >= 1
        int k = (4 * n) / 10; if (k < 1) k = 1;
        int l = (8 * n) / 10;

        float v[8] = {w0[0], w0[1], w0[2], w0[3], w1[0], w1[1], w1[2], w1[3]};
        unsigned key[8], key2[8];
        #pragma unroll
        for (int t = 0; t < 8; ++t) {
            int row = rowb + (t & 3);
            int col = (t >> 2) * 16 + colb;
            unsigned uu = __float_as_uint(v[t]);
            unsigned kk = (uu & 0x80000000u) ? ~uu : (uu | 0x80000000u);
            bool val = (((qwv >> row) & 1u) != 0u) && (((pwv >> col) & 1u) != 0u);
            key[t]  = val ? (kk >> 16)    : 0u;
            key2[t] = val ? ((~kk) >> 16) : 0u;
        }

        // MSB-first radix descent on 16-bit keys
        unsigned T1 = 0u, T2 = 0u;
        for (int bit = 15; bit >= 0; --bit) {
            unsigned c1 = T1 | (1u << bit);
            unsigned c2 = T2 | (1u << bit);
            int cnt1 = 0, cnt2 = 0;
            #pragma unroll
            for (int t = 0; t < 8; ++t) {
                cnt1 += __popcll(__ballot(key[t]  >= c1));
                cnt2 += __popcll(__ballot(key2[t] >= c2));
            }
            if (cnt1 >= k) T1 = c1;
            if (cnt2 >= l) T2 = c2;
        }

        // tie-corrected sums
        float S1 = 0.f, S2 = 0.f;
        int c1n = 0, c2n = 0;
        #pragma unroll
        for (int t = 0; t < 8; ++t) {
            if (key[t]  > T1) S1 += v[t];
            if (key2[t] > T2) S2 += v[t];
            c1n += __popcll(__ballot(key[t]  > T1));
            c2n += __popcll(__ballot(key2[t] > T2));
        }
        #pragma unroll
        for (int off = 32; off > 0; off >>= 1) {
            S1 += __shfl_xor(S1, off, 64);
            S2 += __shfl_xor(S2, off, 64);
        }

        float f1 = key_to_float(T1 << 16);
        float f2 = key_to_float(~(T2 << 16));
        float top = S1 + (float)(k - c1n) * f1;
        float bot = (l > 0) ? (S2 + (float)(l - c2n) * f2) : 0.f;

        if (lane == 0) {
            int bl = pair >> 1, pl = pair & 1;
            logits[(bBase + wr * 2 + bl) * PP + (pBase + wc * 2 + pl)] = aco * top - bco * bot;
        }
    }
}

// ---------- loss = mean_b (lse(logits[b,:]) - logits[b,b]) ----------
__global__ __launch_bounds__(256) void loss_kernel(const float* __restrict__ logits,
                                                   float* __restrict__ loss_out) {
    __shared__ float warr[4];
    const int lane = threadIdx.x & 63;
    const int wid  = threadIdx.x >> 6;
    float acc = 0.f;
    for (int r = wid; r < BQ; r += 4) {
        const float* row = logits + r * PP;
        float x0 = row[lane], x1 = row[lane + 64], x2 = row[lane + 128], x3 = row[lane + 192];
        float m = fmaxf(fmaxf(x0, x1), fmaxf(x2, x3));
        #pragma unroll
        for (int off = 32; off > 0; off >>= 1)
            m = fmaxf(m, __shfl_xor(m, off, 64));
        float s = expf(x0 - m) + expf(x1 - m) + expf(x2 - m) + expf(x3 - m);
        #pragma unroll
        for (int off = 32; off > 0; off >>= 1)
            s += __shfl_xor(s, off, 64);
        float lse = m + logf(s);
        float diag = row[r];
        acc += (lse - diag);
    }
    if (lane == 0) warr[wid] = acc;
    __syncthreads();
    if (threadIdx.x == 0)
        loss_out[0] = (warr[0] + warr[1] + warr[2] + warr[3]) / (float)BQ;
}

extern "C" void kernel_launch(void* const* d_in, const int* in_sizes, int n_in,
                              void* d_out, int out_size, void* d_ws, size_t ws_size,
                              hipStream_t stream) {
    const float* q  = (const float*)d_in[0];
    const float* pe = (const float*)d_in[1];
    const int*   qm = (const int*)d_in[2];
    const int*   pm = (const int*)d_in[3];
    const float* ar = (const float*)d_in[4];
    const float* br = (const float*)d_in[5];
    float* out = (float*)d_out;           // [0] = loss, [1..32768] = logits

    // workspace: qb | pb (bf16 copies)
    char* ws = (char*)d_ws;
    ushort* qb  = (ushort*)ws;
    ushort* pb  = (ushort*)(ws + (size_t)MROWS * DD * 2);

    // 1) convert fp32 -> bf16
    int nq4 = MROWS * DD / 4;
    int np4 = NROWS * DD / 4;
    conv_bf16_v4<<<(nq4 + 255) / 256, 256, 0, stream>>>((const float4*)q,  (ushort4*)qb, nq4);
    conv_bf16_v4<<<(np4 + 255) / 256, 256, 0, stream>>>((const float4*)pe, (ushort4*)pb, np4);

    // 2) fused sim-GEMM + dual top-k -> logits
    dim3 gg(NROWS / BN, MROWS / BM, 1);   // (64, 32) = 2048 blocks = 8/CU
    gemm_select<<<gg, 256, 0, stream>>>(qb, pb, qm, pm, ar, br, out + 1);

    // 3) loss
    loss_kernel<<<1, 256, 0, stream>>>(out + 1, out);
}